// Round 3
// baseline (810.123 us; speedup 1.0000x reference)
//
#include <hip/hip_runtime.h>

// SDE scan: B=2048 rows, T=512 steps, FS=32, FA=16, H=64.
// R3: TWO rows per wave (explicit ILP to hide serial-chain latency),
//     v_pk_fma_f32 packed math ((f,g) MLPs packed per lane; j-pairs in L2),
//     s-broadcast via LDS ds_read_b128 (DS pipe) instead of 48 readlanes,
//     tanh via v_exp_f32 + v_rcp_f32 (no IEEE divide sequence).
// Row pairing makes noise/x0/out accesses perfectly coalesced:
//   wave handles rows (2b, 2b+1); lane<32 -> row 2b comp lane,
//   lane>=32 -> row 2b+1 comp lane-32;  global idx = b*64+lane.

#define SQRT_DT_F 0.22360679774997896f
#define TWO_LOG2E 2.8853900817779268f   // 2*log2(e)

typedef float v2f __attribute__((ext_vector_type(2)));

static __device__ __forceinline__ v2f pk_fma(v2f a, v2f b, v2f c) {
#if __has_builtin(__builtin_elementwise_fma)
    return __builtin_elementwise_fma(a, b, c);
#else
    v2f r; r.x = fmaf(a.x, b.x, c.x); r.y = fmaf(a.y, b.y, c.y); return r;
#endif
}
static __device__ __forceinline__ v2f splat(float s) { v2f r; r.x = s; r.y = s; return r; }

static __device__ __forceinline__ float fexp2(float x) {
#if __has_builtin(__builtin_amdgcn_exp2f)
    return __builtin_amdgcn_exp2f(x);
#else
    return __expf(x * 0.6931471805599453f);
#endif
}
static __device__ __forceinline__ float frcp(float x) {
#if __has_builtin(__builtin_amdgcn_rcpf)
    return __builtin_amdgcn_rcpf(x);
#else
    return 1.0f / x;
#endif
}

// tanh on a packed (f,g) pair: 1 - 2/(exp(2y)+1); stable at both extremes
static __device__ __forceinline__ v2f tanh_pk(v2f y) {
    v2f t = y * splat(TWO_LOG2E);                 // 2y*log2e
    v2f e; e.x = fexp2(t.x); e.y = fexp2(t.y);    // exp(2y)
    v2f d = e + splat(1.0f);
    v2f q; q.x = frcp(d.x); q.y = frcp(d.y);
    return pk_fma(splat(-2.0f), q, splat(1.0f));
}

__device__ __forceinline__ void wave_sync() {
    // Single-wave block: DS pipe is in-order within a wave (verified R1);
    // only stop the compiler moving DS ops across this point. VALU/VMEM/
    // trans may cross freely (mask 0x047F excludes DS read/write bits).
    __builtin_amdgcn_fence(__ATOMIC_SEQ_CST, "wavefront");
    __builtin_amdgcn_sched_barrier(0x047F);
}

__global__ __launch_bounds__(64, 1)
void sde_kernel(const float* __restrict__ in_signal,   // (B,16,512)
                const float* __restrict__ x0v,         // (B,32)
                const float* __restrict__ noise,       // (511,B,32)
                const float* __restrict__ Wf1, const float* __restrict__ bf1,
                const float* __restrict__ Wf2, const float* __restrict__ bf2,
                const float* __restrict__ Wg1, const float* __restrict__ bg1,
                const float* __restrict__ Wg2, const float* __restrict__ bg2,
                float* __restrict__ out)               // (B,32,512)
{
    const int lane = threadIdx.x;     // 0..63
    const int b    = blockIdx.x;      // row-pair index: rows 2b, 2b+1

    // LDS: s0[48] | s1[48] | h0[128] | h1[128]   (s = [a(16), x(32)])
    __shared__ __align__(16) float lds[352];
    float* s0 = lds;
    float* s1 = lds + 48;
    float* h0 = lds + 96;
    float* h1 = lds + 224;

    // ---- weights -> registers (packed (f,g) per lane) ----
    v2f w1[48];
#pragma unroll
    for (int k = 0; k < 48; ++k) {
        w1[k].x = Wf1[k * 64 + lane];
        w1[k].y = Wg1[k * 64 + lane];
    }
    v2f w2v[32];    // lane<32: Wf2 column `lane`; lane>=32: Wg2 column `lane-32`
    {
        const float* W2p = (lane < 32) ? (Wf2 + lane) : (Wg2 + (lane - 32));
#pragma unroll
        for (int p = 0; p < 32; ++p) {
            w2v[p].x = W2p[(2 * p) * 32];
            w2v[p].y = W2p[(2 * p + 1) * 32];
        }
    }
    v2f b1; b1.x = bf1[lane]; b1.y = bg1[lane];
    const float b2 = (lane < 32) ? bf2[lane] : bg2[lane - 32];

    // ---- addresses ----
    const bool lo = (lane < 32);
    const float* a_base  = in_signal + (size_t)(b * 32 + lane) * 512;  // lanes<32
    const float* noise_l = noise + (size_t)b * 64 + lane;              // coalesced
    float* out_ptr = out + (size_t)(b * 64 + lane) * 512;              // coalesced

    float* xw = lds + ((lane >> 5) * 48 + 16 + (lane & 31));           // x slot
    float* aw = lds + (((lane >> 4) & 1) * 48 + (lane & 15));          // a slot (lanes<32)
    const float* hr0 = h0 + ((lane >> 5) << 6);   // hf0 or hg0
    const float* hr1 = h1 + ((lane >> 5) << 6);   // hf1 or hg1

    // ---- init: x0 into LDS; each lane tracks its own (row, comp) series ----
    float xq[4];
    {
        float xi = x0v[(size_t)b * 64 + lane];
        *xw = xi;
        xq[0] = xi;
    }
    float eps_c = noise_l[0];        // t = 0
    float eps_n = noise_l[65536];    // t = 1
    float4 aq = make_float4(0.f, 0.f, 0.f, 0.f);
    float4 aq_n = make_float4(0.f, 0.f, 0.f, 0.f);
    if (lo) aq = *(const float4*)(a_base);

#define L1_ROW(SB, HOUT) do {                                                   \
    v2f a0 = b1, a1 = splat(0.f);                                               \
    _Pragma("unroll")                                                           \
    for (int k0 = 0; k0 < 48; k0 += 4) {                                        \
        const float4 s4 = *(const float4*)&(SB)[k0];                            \
        a0 = pk_fma(splat(s4.x), w1[k0 + 0], a0);                               \
        a1 = pk_fma(splat(s4.y), w1[k0 + 1], a1);                               \
        a0 = pk_fma(splat(s4.z), w1[k0 + 2], a0);                               \
        a1 = pk_fma(splat(s4.w), w1[k0 + 3], a1);                               \
    }                                                                           \
    HOUT = tanh_pk(a0 + a1);                                                    \
} while (0)

#define L2_ROW(HR, RES) do {                                                    \
    v2f A; A.x = b2; A.y = 0.f;                                                 \
    v2f B = splat(0.f);                                                         \
    _Pragma("unroll")                                                           \
    for (int j = 0; j < 64; j += 4) {                                           \
        const float4 h4 = *(const float4*)&(HR)[j];                             \
        v2f hl; hl.x = h4.x; hl.y = h4.y;                                       \
        v2f hh; hh.x = h4.z; hh.y = h4.w;                                       \
        A = pk_fma(hl, w2v[(j >> 1) + 0], A);                                   \
        B = pk_fma(hh, w2v[(j >> 1) + 1], B);                                   \
    }                                                                           \
    v2f S = A + B;                                                              \
    RES = S.x + S.y;                                                            \
} while (0)

#define STEP(tt) do {                                                           \
    /* eps prefetch for t+2 (covers HBM latency across ~2 full steps) */        \
    int tf_ = tq4 + (tt) + 2; if (tf_ > 510) tf_ = 510;                         \
    float eps_f = noise_l[(size_t)tf_ << 16];                                   \
    /* a_t into s-buffers (lanes 0-15 -> row0, 16-31 -> row1) */                \
    if (lo) *aw = ((tt) == 0 ? aq.x : (tt) == 1 ? aq.y                          \
                  : (tt) == 2 ? aq.z : aq.w);                                   \
    wave_sync();                                                                \
    /* layer 1, both rows (independent chains -> ILP) */                        \
    v2f hA, hB;                                                                 \
    L1_ROW(s0, hA);                                                             \
    L1_ROW(s1, hB);                                                             \
    h0[lane] = hA.x; h0[64 + lane] = hA.y;                                      \
    h1[lane] = hB.x; h1[64 + lane] = hB.y;                                      \
    wave_sync();                                                                \
    /* layer 2, both rows: lanes<32 -> drift_i, lanes>=32 -> gpre_i */          \
    float res0, res1;                                                           \
    L2_ROW(hr0, res0);                                                          \
    L2_ROW(hr1, res1);                                                          \
    float sw0 = __shfl_xor(res0, 32, 64);                                       \
    float sw1 = __shfl_xor(res1, 32, 64);                                       \
    /* lanes<32: xi0 = drift0(own) + eps*gpre0(sw); lanes>=32: xi1 sym. */      \
    float dr = lo ? res0 : sw1;                                                 \
    float gp = lo ? sw0 : res1;                                                 \
    float xi = fmaf(gp, eps_c * SQRT_DT_F, dr);                                 \
    xi = fminf(5.0f, fmaxf(-5.0f, xi));                                         \
    *xw = xi;                                                                   \
    xq[((tt) + 1) & 3] = xi;                                                    \
    if ((tt) == 2)                                                              \
        *(float4*)(out_ptr + tq4) = make_float4(xq[0], xq[1], xq[2], xq[3]);    \
    eps_c = eps_n; eps_n = eps_f;                                               \
} while (0)

    // main: t = 0..507 (127 quads)
    for (int tq = 0; tq < 127; ++tq) {
        const int tq4 = tq * 4;
        if (lo) aq_n = *(const float4*)(a_base + tq4 + 4);   // next quad (<=508)
        STEP(0); STEP(1); STEP(2); STEP(3);
        aq = aq_n;
    }
    // tail: t = 508, 509, 510 (store of [508..511] fires at tt==2)
    {
        const int tq4 = 508;
        STEP(0); STEP(1); STEP(2);
    }
#undef STEP
#undef L1_ROW
#undef L2_ROW
}

extern "C" void kernel_launch(void* const* d_in, const int* in_sizes, int n_in,
                              void* d_out, int out_size, void* d_ws, size_t ws_size,
                              hipStream_t stream) {
    // inputs: 0 ts(unused), 1 in_signal, 2 x0, 3 noise, 4 Wf1, 5 bf1, 6 Wf2,
    //         7 bf2, 8 Wg1, 9 bg1, 10 Wg2, 11 bg2
    const float* in_signal = (const float*)d_in[1];
    const float* x0v   = (const float*)d_in[2];
    const float* noise = (const float*)d_in[3];
    const float* Wf1 = (const float*)d_in[4];
    const float* bf1 = (const float*)d_in[5];
    const float* Wf2 = (const float*)d_in[6];
    const float* bf2 = (const float*)d_in[7];
    const float* Wg1 = (const float*)d_in[8];
    const float* bg1 = (const float*)d_in[9];
    const float* Wg2 = (const float*)d_in[10];
    const float* bg2 = (const float*)d_in[11];
    float* out = (float*)d_out;

    hipLaunchKernelGGL(sde_kernel, dim3(1024), dim3(64), 0, stream,
                       in_signal, x0v, noise, Wf1, bf1, Wf2, bf2,
                       Wg1, bg1, Wg2, bg2, out);
}